// Round 16
// baseline (210.783 us; speedup 1.0000x reference)
//
#include <hip/hip_runtime.h>
#include <hip/hip_fp16.h>
#include <math.h>

#define NPB   512      // nodes per bucket (N=102400 = 200*512 exactly)
#define NPBL  9
#define HSTR  5        // accH stride in half2 (gcd(5,32)=1 -> all 32 banks)
#define MAXR  256      // max buckets
#define TILE  2048     // edges per k_p1 block
#define RPT   8        // records per thread in k_p1
#define GCS   16       // gcur/rdone stride in u32 (64B line padding)
#define SLICES 8       // k_p2 slices per bucket

static __device__ __forceinline__ float lrelu(float x) { return x > 0.0f ? x : 0.2f * x; }

static __device__ __forceinline__ unsigned pk2(float a, float b) {
    __half2 h = __floats2half2_rn(a, b);
    return *reinterpret_cast<unsigned*>(&h);
}
static __device__ __forceinline__ float2 up2(unsigned u) {
    __half2 h = *reinterpret_cast<__half2*>(&u);
    return __half22float2(h);
}

// consts layout (floats):
// [1] c_edge, [2..6] va, [7..11] vd, [16..143] bc, [144..783] Wc[5][128]

// ---- setup: fold weights; zero gcur + rdone + epart8 ----
__global__ void k_setup(const float* __restrict__ W_gat, const float* __restrict__ att_src,
                        const float* __restrict__ att_dst, const float* __restrict__ W_edge,
                        const float* __restrict__ att_edge, const float* __restrict__ b_gat,
                        const float* __restrict__ W_fc1, const float* __restrict__ b_fc1,
                        float* __restrict__ consts, unsigned* __restrict__ gcur,
                        unsigned* __restrict__ rdone, float* __restrict__ epart8) {
    int t = threadIdx.x;  // 128 threads
    for (int i = t; i < MAXR * GCS; i += 128) { gcur[i] = 0u; rdone[i] = 0u; }
    if (t < 8) epart8[t] = 0.f;
    if (t == 0) {
        float c = 0.f;
        for (int k = 0; k < 64; k++) c += W_edge[k] * att_edge[k];
        consts[1] = c;
    }
    if (t < 5) {
        float a = 0.f, b = 0.f;
        for (int c = 0; c < 64; c++) {
            float w = W_gat[t * 64 + c];
            a += w * att_src[c];
            b += w * att_dst[c];
        }
        consts[2 + t] = a;
        consts[7 + t] = b;
    }
    float bcv = b_fc1[t];
    for (int c = 0; c < 64; c++) bcv += b_gat[c] * W_fc1[c * 128 + t];
    consts[16 + t] = bcv;
    for (int k = 0; k < 5; k++) {
        float w = 0.f;
        for (int c = 0; c < 64; c++) w += W_gat[k * 64 + c] * W_fc1[c * 128 + t];
        consts[144 + k * 128 + t] = w;
    }
}

// ---- merged: blocks [0,nbl) per-node prep; blocks [nbl,nbl+ebl) edge binning + ea-sum ----
// node: xh = {pk(x0,x1), pk(x2,x3), pk(x4,1.0), f32 a_s} (16B); a_s,a_d f32; fused bstart
__global__ void k_np1(const float* __restrict__ x, const float* __restrict__ consts,
                      uint4* __restrict__ xh, float* __restrict__ a_s, float* __restrict__ a_d,
                      const int* __restrict__ pb, int* __restrict__ bstart,
                      const int* __restrict__ src, const int* __restrict__ dst,
                      const float* __restrict__ ea,
                      uint2* __restrict__ slab, unsigned* __restrict__ gcur,
                      float* __restrict__ epart8,
                      int N, int B, int E, int R, int CAP, int nbl) {
    if ((int)blockIdx.x < nbl) {
        int i = blockIdx.x * blockDim.x + threadIdx.x;
        if (i >= N) return;
        const float* xi = x + (size_t)i * 5;
        float x0 = xi[0], x1 = xi[1], x2 = xi[2], x3 = xi[3], x4 = xi[4];
        float as = x0 * consts[2] + x1 * consts[3] + x2 * consts[4] + x3 * consts[5] + x4 * consts[6];
        float ad = x0 * consts[7] + x1 * consts[8] + x2 * consts[9] + x3 * consts[10] + x4 * consts[11];
        uint4 pkv;
        pkv.x = pk2(x0, x1);
        pkv.y = pk2(x2, x3);
        pkv.z = pk2(x4, 1.0f);
        pkv.w = __float_as_uint(as);
        xh[i] = pkv;
        a_s[i] = as;
        a_d[i] = ad;
        int cur = pb[i];
        int prev = (i == 0) ? -1 : pb[i - 1];
        for (int b = prev + 1; b <= cur; b++) bstart[b] = i;
        if (i == N - 1)
            for (int b = cur + 1; b <= B; b++) bstart[b] = N;
        return;
    }
    __shared__ unsigned hist[MAXR], lbase[MAXR], gbase[MAXR], scan[256];
    __shared__ uint2 staged[TILE];
    __shared__ unsigned char bof[TILE];
    __shared__ float esum[256];
    int t = threadIdx.x;  // 256
    int e0 = ((int)blockIdx.x - nbl) * TILE;
    int n = E - e0; if (n > TILE) n = TILE;
    for (int i = t; i < MAXR; i += 256) hist[i] = 0;
    __syncthreads();
    unsigned key[RPT]; float val[RPT]; unsigned brk[RPT];
    float ce = consts[1];
    float easc = 0.f;
#pragma unroll
    for (int k = 0; k < RPT; k++) {
        int idx = t + k * 256;
        brk[k] = 0xFFFFFFFFu;
        if (idx < n) {
            int e = e0 + idx;
            int d = dst[e];
            unsigned b = (unsigned)d >> NPBL;
            key[k] = ((unsigned)src[e] << NPBL) | ((unsigned)d & (NPB - 1));
            float eav = ea[e];
            easc += eav;
            val[k] = ce * eav;
            unsigned r = atomicAdd(&hist[b], 1u);
            brk[k] = (b << 12) | r;
        }
    }
    __syncthreads();
    unsigned v = (t < R) ? hist[t] : 0;
    if (t < R) gbase[t] = atomicAdd(&gcur[t * GCS], v);
    scan[t] = v;
    __syncthreads();
    for (int off = 1; off < 256; off <<= 1) {
        unsigned add = (t >= off) ? scan[t - off] : 0;
        __syncthreads();
        scan[t] += add;
        __syncthreads();
    }
    if (t < R) lbase[t] = scan[t] - v;
    __syncthreads();
#pragma unroll
    for (int k = 0; k < RPT; k++) {
        if (brk[k] != 0xFFFFFFFFu) {
            unsigned b = brk[k] >> 12, r = brk[k] & 4095u;
            unsigned pos = lbase[b] + r;
            staged[pos] = make_uint2(key[k], __float_as_uint(val[k]));
            bof[pos] = (unsigned char)b;
        }
    }
    __syncthreads();
    for (int i = t; i < n; i += 256) {
        unsigned b = bof[i];
        unsigned slot = gbase[b] + (unsigned)i - lbase[b];
        if (slot < (unsigned)CAP) slab[(size_t)b * CAP + slot] = staged[i];
    }
    // block ea-sum -> epart8 (8 spread accumulators, native global f32 atomic)
    esum[t] = easc;
    __syncthreads();
    for (int o = 128; o > 0; o >>= 1) {
        if (t < o) esum[t] += esum[t + o];
        __syncthreads();
    }
    if (t == 0) unsafeAtomicAdd(&epart8[blockIdx.x & 7], esum[0]);
}

// ---- phase 2 (fused with merge): per (slice s, bucket r) LDS aggregation; the LAST
// slice-block of each bucket merges partials + self-loop and writes y (old k_p3).
// accH[dl*HSTR + c]: c0={ex*x0,ex*x1}, c1={ex*x2,ex*x3}, c2={ex*x4, ex}
// partials layout (SoA, half2): [r][s][3][NPB] u32
__global__ void k_p2(const uint2* __restrict__ slab, const unsigned* __restrict__ gcur,
                     const uint4* __restrict__ xh, const float* __restrict__ a_d,
                     unsigned* __restrict__ partials, const float* __restrict__ epart8,
                     unsigned* __restrict__ rdone,
                     const float* __restrict__ x, const float* __restrict__ a_s,
                     const float* __restrict__ consts, float* __restrict__ y,
                     int S, int CAP, int N, float inv_E) {
    __shared__ __half2 accH[NPB * HSTR];   // 10 KB
    __shared__ float adl[NPB];             // 2 KB
    __shared__ unsigned lastflag;
    int t = threadIdx.x;  // 256
    int s = blockIdx.x, r = blockIdx.y;
    for (int i = t; i < NPB; i += 256) {
        int node = r * NPB + i;
        adl[i] = (node < N) ? a_d[node] : 0.f;
    }
    __half2 z2 = __floats2half2_rn(0.f, 0.f);
    for (int i = t; i < NPB * HSTR; i += 256) accH[i] = z2;
    __syncthreads();
    unsigned cnt = gcur[r * GCS]; if (cnt > (unsigned)CAP) cnt = CAP;
    unsigned L = (cnt + (unsigned)S - 1) / (unsigned)S;
    unsigned i0 = (unsigned)s * L, i1 = i0 + L; if (i1 > cnt) i1 = cnt;
    const uint2* sl = slab + (size_t)r * CAP;
    for (unsigned i = i0 + t; i < i1; i += 256) {
        uint2 rec = sl[i];
        uint4 v = xh[rec.x >> NPBL];
        unsigned dl = rec.x & (NPB - 1);
        float al = __uint_as_float(v.w) + adl[dl] + __uint_as_float(rec.y);
        float ex = __expf(lrelu(al));
        __half2 ex2 = __half2half2(__float2half(ex));
        __half2* a = accH + dl * HSTR;
        unsafeAtomicAdd(a + 0, __hmul2(ex2, *reinterpret_cast<const __half2*>(&v.x)));
        unsafeAtomicAdd(a + 1, __hmul2(ex2, *reinterpret_cast<const __half2*>(&v.y)));
        unsafeAtomicAdd(a + 2, __hmul2(ex2, *reinterpret_cast<const __half2*>(&v.z)));
    }
    __syncthreads();
    // SoA half2 writeout: out[comp*NPB + dl] = accH[dl*HSTR + comp]
    unsigned* out = partials + (size_t)(r * S + s) * (NPB * 3);
    for (int j = t; j < NPB * 3; j += 256) {
        int comp = j >> NPBL, dl = j & (NPB - 1);
        out[j] = *reinterpret_cast<unsigned*>(&accH[dl * HSTR + comp]);
    }
    // ---- last-slice-of-bucket merge (old k_p3 for this bucket) ----
    __syncthreads();
    if (t == 0) {
        __threadfence();   // release: partials visible at agent scope
        unsigned prev = atomicAdd(&rdone[r * GCS], 1u);
        lastflag = (prev == (unsigned)(S - 1)) ? 1u : 0u;
    }
    __syncthreads();
    if (!lastflag) return;
    __threadfence();       // acquire: see other slices' partials
    float se = 0.f;
    for (int k2 = 0; k2 < 8; k2++) se += epart8[k2];
    float mean_ea = se * inv_E;
    float cedge = consts[1];
    for (int dl = t; dl < NPB; dl += 256) {
        int i = r * NPB + dl;
        if (i >= N) break;
        float2 y01 = make_float2(0.f, 0.f), y23 = make_float2(0.f, 0.f), y4s = make_float2(0.f, 0.f);
        const unsigned* p = partials + (size_t)r * S * (NPB * 3) + dl;
        for (int s2 = 0; s2 < S; s2++) {
            const unsigned* q = p + (size_t)s2 * (NPB * 3);
            float2 a = up2(q[0 * NPB]), bv = up2(q[1 * NPB]), c = up2(q[2 * NPB]);
            y01.x += a.x; y01.y += a.y;
            y23.x += bv.x; y23.y += bv.y;
            y4s.x += c.x; y4s.y += c.y;
        }
        const float* xi = x + (size_t)i * 5;
        float x0 = xi[0], x1 = xi[1], x2 = xi[2], x3 = xi[3], x4 = xi[4];
        float aself = lrelu(a_s[i] + adl[dl] + cedge * mean_ea);
        float exs = __expf(aself);
        float inv = 1.f / (y4s.y + exs + 1e-16f);
        y[0 * (size_t)N + i] = (y01.x + exs * x0) * inv;
        y[1 * (size_t)N + i] = (y01.y + exs * x1) * inv;
        y[2 * (size_t)N + i] = (y23.x + exs * x2) * inv;
        y[3 * (size_t)N + i] = (y23.y + exs * x3) * inv;
        y[4 * (size_t)N + i] = (y4s.x + exs * x4) * inv;
    }
}

// ---- fused pool + head: one block per batch row; 512 threads ----
__global__ void k_poolhead(const float* __restrict__ y, const float* __restrict__ consts,
                           const int* __restrict__ bstart, const float* __restrict__ agent_state,
                           const float* __restrict__ W_fc2, const float* __restrict__ b_fc2,
                           const float* __restrict__ W_v1, const float* __restrict__ b_v1,
                           const float* __restrict__ W_v2, const float* __restrict__ b_v2,
                           const float* __restrict__ W_a1, const float* __restrict__ b_a1,
                           const float* __restrict__ W_a2, const float* __restrict__ b_a2,
                           float* __restrict__ out, int A, int B, int N) {
    __shared__ float part[4][128];
    __shared__ float gpart[4][128];
    __shared__ float z[192];
    __shared__ float va[256];      // [0:128) v1s, [128:256) a1s
    __shared__ float red[128];
    __shared__ float advs[8];
    int b = blockIdx.x, t = threadIdx.x;  // 512 threads
    int col = t & 127, grp = t >> 7;
    int st = bstart[b], en = bstart[b + 1];
    int len = en - st;
    // phase A: pool quarter `grp` for channel `col`
    {
        int qlen = (len + 3) >> 2;
        int i0 = st + grp * qlen;
        int i1 = i0 + qlen;
        if (i0 > en) i0 = en;
        if (i1 > en) i1 = en;
        float w0 = consts[144 + col], w1 = consts[272 + col], w2 = consts[400 + col],
              w3 = consts[528 + col], w4 = consts[656 + col];
        float bc = consts[16 + col];
        const float* y0 = y;
        const float* y1p = y + (size_t)N;
        const float* y2p = y + 2 * (size_t)N;
        const float* y3p = y + 3 * (size_t)N;
        const float* y4p = y + 4 * (size_t)N;
        float a0 = 0.f, a1 = 0.f, a2 = 0.f, a3 = 0.f;
        int i = i0;
        for (; i + 3 < i1; i += 4) {
            float h0 = bc + y0[i] * w0 + y1p[i] * w1 + y2p[i] * w2 + y3p[i] * w3 + y4p[i] * w4;
            float h1 = bc + y0[i+1] * w0 + y1p[i+1] * w1 + y2p[i+1] * w2 + y3p[i+1] * w3 + y4p[i+1] * w4;
            float h2 = bc + y0[i+2] * w0 + y1p[i+2] * w1 + y2p[i+2] * w2 + y3p[i+2] * w3 + y4p[i+2] * w4;
            float h3 = bc + y0[i+3] * w0 + y1p[i+3] * w1 + y2p[i+3] * w2 + y3p[i+3] * w3 + y4p[i+3] * w4;
            a0 += fmaxf(h0, 0.f);
            a1 += fmaxf(h1, 0.f);
            a2 += fmaxf(h2, 0.f);
            a3 += fmaxf(h3, 0.f);
        }
        for (; i < i1; ++i) {
            float h = bc + y0[i] * w0 + y1p[i] * w1 + y2p[i] * w2 + y3p[i] * w3 + y4p[i] * w4;
            a0 += fmaxf(h, 0.f);
        }
        part[grp][col] = (a0 + a1) + (a2 + a3);
    }
    __syncthreads();
    // phase B: z assembly + fc2
    if (t < 128) {
        float cnt = (float)len;
        cnt = cnt < 1.f ? 1.f : cnt;
        z[t] = (part[0][t] + part[1][t] + part[2][t] + part[3][t]) / cnt;
    } else if (t < 192) {
        int c = t - 128;
        float a = b_fc2[c];
        const float* as_ = agent_state + b * 34;
        for (int k = 0; k < 34; k++) a += as_[k] * W_fc2[k * 64 + c];
        z[128 + c] = fmaxf(a, 0.f);
    }
    __syncthreads();
    // phase C: grp 0/1 value GEMV halves; grp 2/3 advantage GEMV halves
    {
        const float* W = (grp & 2) ? W_a1 : W_v1;
        int j0 = (grp & 1) * 96;
        float c0 = 0.f, c1 = 0.f, c2 = 0.f, c3 = 0.f;
        for (int j = j0; j < j0 + 96; j += 4) {
            c0 += z[j]     * W[(size_t)j * 128 + col];
            c1 += z[j + 1] * W[(size_t)(j + 1) * 128 + col];
            c2 += z[j + 2] * W[(size_t)(j + 2) * 128 + col];
            c3 += z[j + 3] * W[(size_t)(j + 3) * 128 + col];
        }
        gpart[grp][col] = (c0 + c1) + (c2 + c3);
    }
    __syncthreads();
    if (t < 128) {
        float v = fmaxf(b_v1[t] + gpart[0][t] + gpart[1][t], 0.f);
        va[t] = v;
        red[t] = v * W_v2[t];
    } else if (t < 256) {
        va[t] = fmaxf(b_a1[col] + gpart[2][col] + gpart[3][col], 0.f);
    }
    __syncthreads();
    for (int o = 64; o > 0; o >>= 1) {
        if (t < o) red[t] += red[t + o];
        __syncthreads();
    }
    // advs: one 64-lane wave per output column (A<=7 -> waves 0..6)
    if (t < A * 64) {
        int oc = t >> 6, lane = t & 63;
        float s = va[128 + lane] * W_a2[(size_t)lane * A + oc]
                + va[128 + 64 + lane] * W_a2[(size_t)(64 + lane) * A + oc];
        for (int o = 32; o > 0; o >>= 1) s += __shfl_down(s, o, 64);
        if (lane == 0) advs[oc] = s + b_a2[oc];
    }
    __syncthreads();
    if (t == 0) {
        float value = red[0] + b_v2[0];
        float m = 0.f;
        for (int j = 0; j < A; j++) m += advs[j];
        m *= (1.f / (float)A);
        for (int j = 0; j < A; j++) out[b * A + j] = value + advs[j] - m;
    }
}

extern "C" void kernel_launch(void* const* d_in, const int* in_sizes, int n_in,
                              void* d_out, int out_size, void* d_ws, size_t ws_size,
                              hipStream_t stream) {
    const float* x        = (const float*)d_in[0];
    const int* edge_index = (const int*)d_in[1];
    const float* ea       = (const float*)d_in[2];
    const float* agent    = (const float*)d_in[3];
    const int* pool_batch = (const int*)d_in[4];
    const float* W_gat    = (const float*)d_in[5];
    const float* att_src  = (const float*)d_in[6];
    const float* att_dst  = (const float*)d_in[7];
    const float* W_edge   = (const float*)d_in[8];
    const float* att_edge = (const float*)d_in[9];
    const float* b_gat    = (const float*)d_in[10];
    const float* W_fc1    = (const float*)d_in[11];
    const float* b_fc1    = (const float*)d_in[12];
    const float* W_fc2    = (const float*)d_in[13];
    const float* b_fc2    = (const float*)d_in[14];
    const float* W_v1     = (const float*)d_in[15];
    const float* b_v1     = (const float*)d_in[16];
    const float* W_v2     = (const float*)d_in[17];
    const float* b_v2     = (const float*)d_in[18];
    const float* W_a1     = (const float*)d_in[19];
    const float* b_a1     = (const float*)d_in[20];
    const float* W_a2     = (const float*)d_in[21];
    const float* b_a2     = (const float*)d_in[22];

    const int N = in_sizes[0] / 5;
    const int E = in_sizes[2];
    const int B = in_sizes[3] / 34;
    const int A = out_size / B;
    const float inv_E = 1.0f / (float)E;

    const int* src = edge_index;
    const int* dst = edge_index + E;

    const int R = (N + NPB - 1) / NPB;            // 200 buckets
    int capBase = (E + R - 1) / R;                // ~8192
    const int CAP = capBase + capBase / 16 + 256;

    // ---- ws layout (no host-side zeroing; k_setup zeroes gcur/rdone/epart8) ----
    char* ws = (char*)d_ws;
    size_t off = 0;
    auto take = [&](size_t bytes) {
        size_t o = off;
        off = (off + bytes + 255) & ~(size_t)255;
        return o;
    };
    size_t o_consts = take(4096);
    size_t o_gcur   = take((size_t)MAXR * GCS * 4);
    size_t o_rdone  = take((size_t)MAXR * GCS * 4);
    size_t o_epart8 = take(8 * 4);
    size_t o_xh     = take((size_t)N * 16);
    size_t o_as     = take((size_t)N * 4);
    size_t o_ad     = take((size_t)N * 4);
    size_t o_y      = take((size_t)N * 5 * 4);
    size_t o_bstart = take((size_t)(B + 1) * 4);
    size_t o_slab   = take((size_t)R * CAP * 8);
    size_t o_part   = off;
    size_t perS = (size_t)R * NPB * 3 * 4;   // half2 partials
    int S = SLICES;
    while (S > 1 && o_part + (size_t)S * perS > ws_size) S--;

    float* consts   = (float*)(ws + o_consts);
    unsigned* gcur  = (unsigned*)(ws + o_gcur);
    unsigned* rdone = (unsigned*)(ws + o_rdone);
    float* epart8   = (float*)(ws + o_epart8);
    uint4* xh       = (uint4*)(ws + o_xh);
    float* a_s      = (float*)(ws + o_as);
    float* a_d      = (float*)(ws + o_ad);
    float* y        = (float*)(ws + o_y);
    int* bstart     = (int*)(ws + o_bstart);
    uint2* slab     = (uint2*)(ws + o_slab);
    unsigned* partials = (unsigned*)(ws + o_part);

    k_setup<<<1, 128, 0, stream>>>(W_gat, att_src, att_dst, W_edge, att_edge, b_gat,
                                   W_fc1, b_fc1, consts, gcur, rdone, epart8);

    int nbl = (N + 255) / 256;
    int ebl = (E + TILE - 1) / TILE;
    k_np1<<<nbl + ebl, 256, 0, stream>>>(x, consts, xh, a_s, a_d, pool_batch, bstart,
                                         src, dst, ea, slab, gcur, epart8,
                                         N, B, E, R, CAP, nbl);
    dim3 g2grid(S, R);
    k_p2<<<g2grid, 256, 0, stream>>>(slab, gcur, xh, a_d, partials, epart8, rdone,
                                     x, a_s, consts, y, S, CAP, N, inv_E);
    k_poolhead<<<B, 512, 0, stream>>>(y, consts, bstart, agent, W_fc2, b_fc2,
                                      W_v1, b_v1, W_v2, b_v2, W_a1, b_a1, W_a2, b_a2,
                                      (float*)d_out, A, B, N);
}

// Round 17
// 103.636 us; speedup vs baseline: 2.0339x; 2.0339x over previous
//
#include <hip/hip_runtime.h>
#include <hip/hip_fp16.h>
#include <math.h>

#define NPB   512      // nodes per bucket (N=102400 = 200*512 exactly)
#define NPBL  9
#define HSTR  5        // accH stride in half2 (gcd(5,32)=1 -> all 32 banks)
#define MAXR  256      // max buckets
#define TILE  2048     // edges per k_p1 block
#define RPT   8        // records per thread in k_p1
#define GCS   16       // gcur stride in u32 (64B line padding)
#define SLICES 8       // k_p2 slices per bucket

static __device__ __forceinline__ float lrelu(float x) { return x > 0.0f ? x : 0.2f * x; }

static __device__ __forceinline__ unsigned pk2(float a, float b) {
    __half2 h = __floats2half2_rn(a, b);
    return *reinterpret_cast<unsigned*>(&h);
}
static __device__ __forceinline__ float2 up2(unsigned u) {
    __half2 h = *reinterpret_cast<__half2*>(&u);
    return __half22float2(h);
}

// consts layout (floats):
// [0] sum_ea (written by k_p2 block(0,0)), [1] c_edge, [2..6] va, [7..11] vd,
// [16..143] bc, [144..783] Wc[5][128]

// ---- setup: fold weights; zero gcur + epart8 ----
__global__ void k_setup(const float* __restrict__ W_gat, const float* __restrict__ att_src,
                        const float* __restrict__ att_dst, const float* __restrict__ W_edge,
                        const float* __restrict__ att_edge, const float* __restrict__ b_gat,
                        const float* __restrict__ W_fc1, const float* __restrict__ b_fc1,
                        float* __restrict__ consts, unsigned* __restrict__ gcur,
                        float* __restrict__ epart8) {
    int t = threadIdx.x;  // 128 threads
    for (int i = t; i < MAXR * GCS; i += 128) gcur[i] = 0u;
    if (t < 8) epart8[t] = 0.f;
    if (t == 0) {
        float c = 0.f;
        for (int k = 0; k < 64; k++) c += W_edge[k] * att_edge[k];
        consts[1] = c;
    }
    if (t < 5) {
        float a = 0.f, b = 0.f;
        for (int c = 0; c < 64; c++) {
            float w = W_gat[t * 64 + c];
            a += w * att_src[c];
            b += w * att_dst[c];
        }
        consts[2 + t] = a;
        consts[7 + t] = b;
    }
    float bcv = b_fc1[t];
    for (int c = 0; c < 64; c++) bcv += b_gat[c] * W_fc1[c * 128 + t];
    consts[16 + t] = bcv;
    for (int k = 0; k < 5; k++) {
        float w = 0.f;
        for (int c = 0; c < 64; c++) w += W_gat[k * 64 + c] * W_fc1[c * 128 + t];
        consts[144 + k * 128 + t] = w;
    }
}

// ---- merged: blocks [0,nbl) per-node prep; blocks [nbl,nbl+ebl) edge binning + ea-sum ----
// node: xh = {pk(x0,x1), pk(x2,x3), pk(x4,1.0), f32 a_s} (16B); a_s,a_d f32; fused bstart
__global__ void k_np1(const float* __restrict__ x, const float* __restrict__ consts,
                      uint4* __restrict__ xh, float* __restrict__ a_s, float* __restrict__ a_d,
                      const int* __restrict__ pb, int* __restrict__ bstart,
                      const int* __restrict__ src, const int* __restrict__ dst,
                      const float* __restrict__ ea,
                      uint2* __restrict__ slab, unsigned* __restrict__ gcur,
                      float* __restrict__ epart8,
                      int N, int B, int E, int R, int CAP, int nbl) {
    if ((int)blockIdx.x < nbl) {
        int i = blockIdx.x * blockDim.x + threadIdx.x;
        if (i >= N) return;
        const float* xi = x + (size_t)i * 5;
        float x0 = xi[0], x1 = xi[1], x2 = xi[2], x3 = xi[3], x4 = xi[4];
        float as = x0 * consts[2] + x1 * consts[3] + x2 * consts[4] + x3 * consts[5] + x4 * consts[6];
        float ad = x0 * consts[7] + x1 * consts[8] + x2 * consts[9] + x3 * consts[10] + x4 * consts[11];
        uint4 pkv;
        pkv.x = pk2(x0, x1);
        pkv.y = pk2(x2, x3);
        pkv.z = pk2(x4, 1.0f);
        pkv.w = __float_as_uint(as);
        xh[i] = pkv;
        a_s[i] = as;
        a_d[i] = ad;
        int cur = pb[i];
        int prev = (i == 0) ? -1 : pb[i - 1];
        for (int b = prev + 1; b <= cur; b++) bstart[b] = i;
        if (i == N - 1)
            for (int b = cur + 1; b <= B; b++) bstart[b] = N;
        return;
    }
    __shared__ unsigned hist[MAXR], lbase[MAXR], gbase[MAXR], scan[256];
    __shared__ uint2 staged[TILE];
    __shared__ unsigned char bof[TILE];
    __shared__ float esum[256];
    int t = threadIdx.x;  // 256
    int e0 = ((int)blockIdx.x - nbl) * TILE;
    int n = E - e0; if (n > TILE) n = TILE;
    for (int i = t; i < MAXR; i += 256) hist[i] = 0;
    __syncthreads();
    unsigned key[RPT]; float val[RPT]; unsigned brk[RPT];
    float ce = consts[1];
    float easc = 0.f;
#pragma unroll
    for (int k = 0; k < RPT; k++) {
        int idx = t + k * 256;
        brk[k] = 0xFFFFFFFFu;
        if (idx < n) {
            int e = e0 + idx;
            int d = dst[e];
            unsigned b = (unsigned)d >> NPBL;
            key[k] = ((unsigned)src[e] << NPBL) | ((unsigned)d & (NPB - 1));
            float eav = ea[e];
            easc += eav;
            val[k] = ce * eav;
            unsigned r = atomicAdd(&hist[b], 1u);
            brk[k] = (b << 12) | r;
        }
    }
    __syncthreads();
    unsigned v = (t < R) ? hist[t] : 0;
    if (t < R) gbase[t] = atomicAdd(&gcur[t * GCS], v);
    scan[t] = v;
    __syncthreads();
    for (int off = 1; off < 256; off <<= 1) {
        unsigned add = (t >= off) ? scan[t - off] : 0;
        __syncthreads();
        scan[t] += add;
        __syncthreads();
    }
    if (t < R) lbase[t] = scan[t] - v;
    __syncthreads();
#pragma unroll
    for (int k = 0; k < RPT; k++) {
        if (brk[k] != 0xFFFFFFFFu) {
            unsigned b = brk[k] >> 12, r = brk[k] & 4095u;
            unsigned pos = lbase[b] + r;
            staged[pos] = make_uint2(key[k], __float_as_uint(val[k]));
            bof[pos] = (unsigned char)b;
        }
    }
    __syncthreads();
    for (int i = t; i < n; i += 256) {
        unsigned b = bof[i];
        unsigned slot = gbase[b] + (unsigned)i - lbase[b];
        if (slot < (unsigned)CAP) slab[(size_t)b * CAP + slot] = staged[i];
    }
    // block ea-sum -> epart8 (8 spread accumulators, native global f32 atomic)
    esum[t] = easc;
    __syncthreads();
    for (int o = 128; o > 0; o >>= 1) {
        if (t < o) esum[t] += esum[t + o];
        __syncthreads();
    }
    if (t == 0) unsafeAtomicAdd(&epart8[blockIdx.x & 7], esum[0]);
}

// ---- phase 2: per (slice s, bucket r): LDS aggregation; 3 packed-f16 atomics/record ----
// accH[dl*HSTR + c]: c0={ex*x0,ex*x1}, c1={ex*x2,ex*x3}, c2={ex*x4, ex}
// partials layout (SoA, half2): [r][s][3][NPB] u32
__global__ void k_p2(const uint2* __restrict__ slab, const unsigned* __restrict__ gcur,
                     const uint4* __restrict__ xh, const float* __restrict__ a_d,
                     unsigned* __restrict__ partials, const float* __restrict__ epart8,
                     float* __restrict__ consts_w, int S, int CAP, int N) {
    __shared__ __half2 accH[NPB * HSTR];   // 10 KB
    __shared__ float adl[NPB];             // 2 KB
    int t = threadIdx.x;  // 256
    int s = blockIdx.x, r = blockIdx.y;
    if (s == 0 && r == 0 && t == 0) {
        float se = 0.f;
        for (int i = 0; i < 8; i++) se += epart8[i];
        consts_w[0] = se;   // consumed by k_p3 (next kernel)
    }
    for (int i = t; i < NPB; i += 256) {
        int node = r * NPB + i;
        adl[i] = (node < N) ? a_d[node] : 0.f;
    }
    __half2 z2 = __floats2half2_rn(0.f, 0.f);
    for (int i = t; i < NPB * HSTR; i += 256) accH[i] = z2;
    __syncthreads();
    unsigned cnt = gcur[r * GCS]; if (cnt > (unsigned)CAP) cnt = CAP;
    unsigned L = (cnt + (unsigned)S - 1) / (unsigned)S;
    unsigned i0 = (unsigned)s * L, i1 = i0 + L; if (i1 > cnt) i1 = cnt;
    const uint2* sl = slab + (size_t)r * CAP;
    for (unsigned i = i0 + t; i < i1; i += 256) {
        uint2 rec = sl[i];
        uint4 v = xh[rec.x >> NPBL];
        unsigned dl = rec.x & (NPB - 1);
        float al = __uint_as_float(v.w) + adl[dl] + __uint_as_float(rec.y);
        float ex = __expf(lrelu(al));
        __half2 ex2 = __half2half2(__float2half(ex));
        __half2* a = accH + dl * HSTR;
        unsafeAtomicAdd(a + 0, __hmul2(ex2, *reinterpret_cast<const __half2*>(&v.x)));
        unsafeAtomicAdd(a + 1, __hmul2(ex2, *reinterpret_cast<const __half2*>(&v.y)));
        unsafeAtomicAdd(a + 2, __hmul2(ex2, *reinterpret_cast<const __half2*>(&v.z)));
    }
    __syncthreads();
    // SoA half2 writeout: out[comp*NPB + dl] = accH[dl*HSTR + comp]
    unsigned* out = partials + (size_t)(r * S + s) * (NPB * 3);
    for (int j = t; j < NPB * 3; j += 256) {
        int comp = j >> NPBL, dl = j & (NPB - 1);
        out[j] = *reinterpret_cast<unsigned*>(&accH[dl * HSTR + comp]);
    }
}

// ---- phase 3: merge S half2 partials + self-loop, normalize -> y SoA [5][N] ----
__global__ void k_p3(const unsigned* __restrict__ partials, const float* __restrict__ x,
                     const float* __restrict__ a_s, const float* __restrict__ a_d,
                     const float* __restrict__ consts, float* __restrict__ y,
                     int N, int S, float inv_E) {
    int i = blockIdx.x * blockDim.x + threadIdx.x;
    if (i >= N) return;
    int r = i >> NPBL, dl = i & (NPB - 1);
    float2 y01 = make_float2(0.f, 0.f), y23 = make_float2(0.f, 0.f), y4s = make_float2(0.f, 0.f);
    const unsigned* p = partials + (size_t)r * S * (NPB * 3) + dl;
    for (int s = 0; s < S; s++) {
        const unsigned* q = p + (size_t)s * (NPB * 3);
        float2 a = up2(q[0 * NPB]), b = up2(q[1 * NPB]), c = up2(q[2 * NPB]);
        y01.x += a.x; y01.y += a.y;
        y23.x += b.x; y23.y += b.y;
        y4s.x += c.x; y4s.y += c.y;
    }
    const float* xi = x + (size_t)i * 5;
    float x0 = xi[0], x1 = xi[1], x2 = xi[2], x3 = xi[3], x4 = xi[4];
    float mean_ea = consts[0] * inv_E;
    float aself = lrelu(a_s[i] + a_d[i] + consts[1] * mean_ea);
    float exs = __expf(aself);
    float inv = 1.f / (y4s.y + exs + 1e-16f);
    y[0 * (size_t)N + i] = (y01.x + exs * x0) * inv;
    y[1 * (size_t)N + i] = (y01.y + exs * x1) * inv;
    y[2 * (size_t)N + i] = (y23.x + exs * x2) * inv;
    y[3 * (size_t)N + i] = (y23.y + exs * x3) * inv;
    y[4 * (size_t)N + i] = (y4s.x + exs * x4) * inv;
}

// ---- fused pool + head: one block per batch row; 512 threads ----
__global__ void k_poolhead(const float* __restrict__ y, const float* __restrict__ consts,
                           const int* __restrict__ bstart, const float* __restrict__ agent_state,
                           const float* __restrict__ W_fc2, const float* __restrict__ b_fc2,
                           const float* __restrict__ W_v1, const float* __restrict__ b_v1,
                           const float* __restrict__ W_v2, const float* __restrict__ b_v2,
                           const float* __restrict__ W_a1, const float* __restrict__ b_a1,
                           const float* __restrict__ W_a2, const float* __restrict__ b_a2,
                           float* __restrict__ out, int A, int B, int N) {
    __shared__ float part[4][128];
    __shared__ float gpart[4][128];
    __shared__ float z[192];
    __shared__ float va[256];      // [0:128) v1s, [128:256) a1s
    __shared__ float red[128];
    __shared__ float advs[8];
    int b = blockIdx.x, t = threadIdx.x;  // 512 threads
    int col = t & 127, grp = t >> 7;
    int st = bstart[b], en = bstart[b + 1];
    int len = en - st;
    // phase A: pool quarter `grp` for channel `col`
    {
        int qlen = (len + 3) >> 2;
        int i0 = st + grp * qlen;
        int i1 = i0 + qlen;
        if (i0 > en) i0 = en;
        if (i1 > en) i1 = en;
        float w0 = consts[144 + col], w1 = consts[272 + col], w2 = consts[400 + col],
              w3 = consts[528 + col], w4 = consts[656 + col];
        float bc = consts[16 + col];
        const float* y0 = y;
        const float* y1p = y + (size_t)N;
        const float* y2p = y + 2 * (size_t)N;
        const float* y3p = y + 3 * (size_t)N;
        const float* y4p = y + 4 * (size_t)N;
        float a0 = 0.f, a1 = 0.f, a2 = 0.f, a3 = 0.f;
        int i = i0;
        for (; i + 3 < i1; i += 4) {
            float h0 = bc + y0[i] * w0 + y1p[i] * w1 + y2p[i] * w2 + y3p[i] * w3 + y4p[i] * w4;
            float h1 = bc + y0[i+1] * w0 + y1p[i+1] * w1 + y2p[i+1] * w2 + y3p[i+1] * w3 + y4p[i+1] * w4;
            float h2 = bc + y0[i+2] * w0 + y1p[i+2] * w1 + y2p[i+2] * w2 + y3p[i+2] * w3 + y4p[i+2] * w4;
            float h3 = bc + y0[i+3] * w0 + y1p[i+3] * w1 + y2p[i+3] * w2 + y3p[i+3] * w3 + y4p[i+3] * w4;
            a0 += fmaxf(h0, 0.f);
            a1 += fmaxf(h1, 0.f);
            a2 += fmaxf(h2, 0.f);
            a3 += fmaxf(h3, 0.f);
        }
        for (; i < i1; ++i) {
            float h = bc + y0[i] * w0 + y1p[i] * w1 + y2p[i] * w2 + y3p[i] * w3 + y4p[i] * w4;
            a0 += fmaxf(h, 0.f);
        }
        part[grp][col] = (a0 + a1) + (a2 + a3);
    }
    __syncthreads();
    // phase B: z assembly + fc2
    if (t < 128) {
        float cnt = (float)len;
        cnt = cnt < 1.f ? 1.f : cnt;
        z[t] = (part[0][t] + part[1][t] + part[2][t] + part[3][t]) / cnt;
    } else if (t < 192) {
        int c = t - 128;
        float a = b_fc2[c];
        const float* as_ = agent_state + b * 34;
        for (int k = 0; k < 34; k++) a += as_[k] * W_fc2[k * 64 + c];
        z[128 + c] = fmaxf(a, 0.f);
    }
    __syncthreads();
    // phase C: grp 0/1 value GEMV halves; grp 2/3 advantage GEMV halves
    {
        const float* W = (grp & 2) ? W_a1 : W_v1;
        int j0 = (grp & 1) * 96;
        float c0 = 0.f, c1 = 0.f, c2 = 0.f, c3 = 0.f;
        for (int j = j0; j < j0 + 96; j += 4) {
            c0 += z[j]     * W[(size_t)j * 128 + col];
            c1 += z[j + 1] * W[(size_t)(j + 1) * 128 + col];
            c2 += z[j + 2] * W[(size_t)(j + 2) * 128 + col];
            c3 += z[j + 3] * W[(size_t)(j + 3) * 128 + col];
        }
        gpart[grp][col] = (c0 + c1) + (c2 + c3);
    }
    __syncthreads();
    if (t < 128) {
        float v = fmaxf(b_v1[t] + gpart[0][t] + gpart[1][t], 0.f);
        va[t] = v;
        red[t] = v * W_v2[t];
    } else if (t < 256) {
        va[t] = fmaxf(b_a1[col] + gpart[2][col] + gpart[3][col], 0.f);
    }
    __syncthreads();
    for (int o = 64; o > 0; o >>= 1) {
        if (t < o) red[t] += red[t + o];
        __syncthreads();
    }
    // advs: one 64-lane wave per output column (A<=7 -> waves 0..6)
    if (t < A * 64) {
        int oc = t >> 6, lane = t & 63;
        float s = va[128 + lane] * W_a2[(size_t)lane * A + oc]
                + va[128 + 64 + lane] * W_a2[(size_t)(64 + lane) * A + oc];
        for (int o = 32; o > 0; o >>= 1) s += __shfl_down(s, o, 64);
        if (lane == 0) advs[oc] = s + b_a2[oc];
    }
    __syncthreads();
    if (t == 0) {
        float value = red[0] + b_v2[0];
        float m = 0.f;
        for (int j = 0; j < A; j++) m += advs[j];
        m *= (1.f / (float)A);
        for (int j = 0; j < A; j++) out[b * A + j] = value + advs[j] - m;
    }
}

extern "C" void kernel_launch(void* const* d_in, const int* in_sizes, int n_in,
                              void* d_out, int out_size, void* d_ws, size_t ws_size,
                              hipStream_t stream) {
    const float* x        = (const float*)d_in[0];
    const int* edge_index = (const int*)d_in[1];
    const float* ea       = (const float*)d_in[2];
    const float* agent    = (const float*)d_in[3];
    const int* pool_batch = (const int*)d_in[4];
    const float* W_gat    = (const float*)d_in[5];
    const float* att_src  = (const float*)d_in[6];
    const float* att_dst  = (const float*)d_in[7];
    const float* W_edge   = (const float*)d_in[8];
    const float* att_edge = (const float*)d_in[9];
    const float* b_gat    = (const float*)d_in[10];
    const float* W_fc1    = (const float*)d_in[11];
    const float* b_fc1    = (const float*)d_in[12];
    const float* W_fc2    = (const float*)d_in[13];
    const float* b_fc2    = (const float*)d_in[14];
    const float* W_v1     = (const float*)d_in[15];
    const float* b_v1     = (const float*)d_in[16];
    const float* W_v2     = (const float*)d_in[17];
    const float* b_v2     = (const float*)d_in[18];
    const float* W_a1     = (const float*)d_in[19];
    const float* b_a1     = (const float*)d_in[20];
    const float* W_a2     = (const float*)d_in[21];
    const float* b_a2     = (const float*)d_in[22];

    const int N = in_sizes[0] / 5;
    const int E = in_sizes[2];
    const int B = in_sizes[3] / 34;
    const int A = out_size / B;
    const float inv_E = 1.0f / (float)E;

    const int* src = edge_index;
    const int* dst = edge_index + E;

    const int R = (N + NPB - 1) / NPB;            // 200 buckets
    int capBase = (E + R - 1) / R;                // ~8192
    const int CAP = capBase + capBase / 16 + 256;

    // ---- ws layout (no host-side zeroing; k_setup zeroes gcur/epart8) ----
    char* ws = (char*)d_ws;
    size_t off = 0;
    auto take = [&](size_t bytes) {
        size_t o = off;
        off = (off + bytes + 255) & ~(size_t)255;
        return o;
    };
    size_t o_consts = take(4096);
    size_t o_gcur   = take((size_t)MAXR * GCS * 4);
    size_t o_epart8 = take(8 * 4);
    size_t o_xh     = take((size_t)N * 16);
    size_t o_as     = take((size_t)N * 4);
    size_t o_ad     = take((size_t)N * 4);
    size_t o_y      = take((size_t)N * 5 * 4);
    size_t o_bstart = take((size_t)(B + 1) * 4);
    size_t o_slab   = take((size_t)R * CAP * 8);
    size_t o_part   = off;
    size_t perS = (size_t)R * NPB * 3 * 4;   // half2 partials
    int S = SLICES;
    while (S > 1 && o_part + (size_t)S * perS > ws_size) S--;

    float* consts   = (float*)(ws + o_consts);
    unsigned* gcur  = (unsigned*)(ws + o_gcur);
    float* epart8   = (float*)(ws + o_epart8);
    uint4* xh       = (uint4*)(ws + o_xh);
    float* a_s      = (float*)(ws + o_as);
    float* a_d      = (float*)(ws + o_ad);
    float* y        = (float*)(ws + o_y);
    int* bstart     = (int*)(ws + o_bstart);
    uint2* slab     = (uint2*)(ws + o_slab);
    unsigned* partials = (unsigned*)(ws + o_part);

    k_setup<<<1, 128, 0, stream>>>(W_gat, att_src, att_dst, W_edge, att_edge, b_gat,
                                   W_fc1, b_fc1, consts, gcur, epart8);

    int nbl = (N + 255) / 256;
    int ebl = (E + TILE - 1) / TILE;
    k_np1<<<nbl + ebl, 256, 0, stream>>>(x, consts, xh, a_s, a_d, pool_batch, bstart,
                                         src, dst, ea, slab, gcur, epart8,
                                         N, B, E, R, CAP, nbl);
    dim3 g2grid(S, R);
    k_p2<<<g2grid, 256, 0, stream>>>(slab, gcur, xh, a_d, partials, epart8, consts, S, CAP, N);
    k_p3<<<nbl, 256, 0, stream>>>(partials, x, a_s, a_d, consts, y, N, S, inv_E);
    k_poolhead<<<B, 512, 0, stream>>>(y, consts, bstart, agent, W_fc2, b_fc2,
                                      W_v1, b_v1, W_v2, b_v2, W_a1, b_a1, W_a2, b_a2,
                                      (float*)d_out, A, B, N);
}

// Round 18
// 103.534 us; speedup vs baseline: 2.0359x; 1.0010x over previous
//
#include <hip/hip_runtime.h>
#include <hip/hip_fp16.h>
#include <math.h>

#define NPB   512      // nodes per bucket (N=102400 = 200*512 exactly)
#define NPBL  9
#define HSTR  5        // accH stride in half2 (gcd(5,32)=1 -> all 32 banks)
#define MAXR  256      // max buckets
#define TILE  2048     // edges per k_np1 edge-block
#define RPT   4        // records per thread (512 threads)
#define GCS   16       // gcur stride in u32 (64B line padding)
#define SLICES 8       // k_p2 slices per bucket

static __device__ __forceinline__ float lrelu(float x) { return x > 0.0f ? x : 0.2f * x; }

static __device__ __forceinline__ unsigned pk2(float a, float b) {
    __half2 h = __floats2half2_rn(a, b);
    return *reinterpret_cast<unsigned*>(&h);
}
static __device__ __forceinline__ float2 up2(unsigned u) {
    __half2 h = *reinterpret_cast<__half2*>(&u);
    return __half22float2(h);
}

// consts layout (floats):
// [0] sum_ea (written by k_p2 block(0,0)), [1] c_edge, [2..6] va, [7..11] vd,
// [16..143] bc, [144..783] Wc[5][128]

// ---- setup: fold weights; zero gcur + epart8 ----
__global__ void k_setup(const float* __restrict__ W_gat, const float* __restrict__ att_src,
                        const float* __restrict__ att_dst, const float* __restrict__ W_edge,
                        const float* __restrict__ att_edge, const float* __restrict__ b_gat,
                        const float* __restrict__ W_fc1, const float* __restrict__ b_fc1,
                        float* __restrict__ consts, unsigned* __restrict__ gcur,
                        float* __restrict__ epart8) {
    int t = threadIdx.x;  // 128 threads
    for (int i = t; i < MAXR * GCS; i += 128) gcur[i] = 0u;
    if (t < 8) epart8[t] = 0.f;
    if (t == 0) {
        float c = 0.f;
        for (int k = 0; k < 64; k++) c += W_edge[k] * att_edge[k];
        consts[1] = c;
    }
    if (t < 5) {
        float a = 0.f, b = 0.f;
        for (int c = 0; c < 64; c++) {
            float w = W_gat[t * 64 + c];
            a += w * att_src[c];
            b += w * att_dst[c];
        }
        consts[2 + t] = a;
        consts[7 + t] = b;
    }
    float bcv = b_fc1[t];
    for (int c = 0; c < 64; c++) bcv += b_gat[c] * W_fc1[c * 128 + t];
    consts[16 + t] = bcv;
    for (int k = 0; k < 5; k++) {
        float w = 0.f;
        for (int c = 0; c < 64; c++) w += W_gat[k * 64 + c] * W_fc1[c * 128 + t];
        consts[144 + k * 128 + t] = w;
    }
}

// ---- merged: blocks [0,nbl) per-node prep; blocks [nbl,nbl+ebl) edge binning + ea-sum ----
// 512 threads/block. node: xh = {pk(x0,x1), pk(x2,x3), pk(x4,1.0), f32 a_s}; fused bstart
__global__ void k_np1(const float* __restrict__ x, const float* __restrict__ consts,
                      uint4* __restrict__ xh, float* __restrict__ a_s, float* __restrict__ a_d,
                      const int* __restrict__ pb, int* __restrict__ bstart,
                      const int* __restrict__ src, const int* __restrict__ dst,
                      const float* __restrict__ ea,
                      uint2* __restrict__ slab, unsigned* __restrict__ gcur,
                      float* __restrict__ epart8,
                      int N, int B, int E, int R, int CAP, int nbl) {
    if ((int)blockIdx.x < nbl) {
        int i = blockIdx.x * blockDim.x + threadIdx.x;
        if (i >= N) return;
        const float* xi = x + (size_t)i * 5;
        float x0 = xi[0], x1 = xi[1], x2 = xi[2], x3 = xi[3], x4 = xi[4];
        float as = x0 * consts[2] + x1 * consts[3] + x2 * consts[4] + x3 * consts[5] + x4 * consts[6];
        float ad = x0 * consts[7] + x1 * consts[8] + x2 * consts[9] + x3 * consts[10] + x4 * consts[11];
        uint4 pkv;
        pkv.x = pk2(x0, x1);
        pkv.y = pk2(x2, x3);
        pkv.z = pk2(x4, 1.0f);
        pkv.w = __float_as_uint(as);
        xh[i] = pkv;
        a_s[i] = as;
        a_d[i] = ad;
        int cur = pb[i];
        int prev = (i == 0) ? -1 : pb[i - 1];
        for (int b = prev + 1; b <= cur; b++) bstart[b] = i;
        if (i == N - 1)
            for (int b = cur + 1; b <= B; b++) bstart[b] = N;
        return;
    }
    __shared__ unsigned hist[MAXR], lbase[MAXR], gbase[MAXR], wsum[4];
    __shared__ uint2 staged[TILE];
    __shared__ unsigned char bof[TILE];
    __shared__ float esum[512];
    int t = threadIdx.x;  // 512
    int e0 = ((int)blockIdx.x - nbl) * TILE;
    int n = E - e0; if (n > TILE) n = TILE;
    if (t < MAXR) hist[t] = 0;
    __syncthreads();
    unsigned key[RPT]; float val[RPT]; unsigned brk[RPT];
    float ce = consts[1];
    float easc = 0.f;
#pragma unroll
    for (int k = 0; k < RPT; k++) {
        int idx = t + k * 512;
        brk[k] = 0xFFFFFFFFu;
        if (idx < n) {
            int e = e0 + idx;
            int d = dst[e];
            unsigned b = (unsigned)d >> NPBL;
            key[k] = ((unsigned)src[e] << NPBL) | ((unsigned)d & (NPB - 1));
            float eav = ea[e];
            easc += eav;
            val[k] = ce * eav;
            unsigned r = atomicAdd(&hist[b], 1u);
            brk[k] = (b << 12) | r;
        }
    }
    __syncthreads();
    // scan over hist[0..255] via wave shfl (threads 0..255 = 4 waves), 2 barriers
    unsigned v = 0, incl = 0;
    if (t < MAXR) {
        v = hist[t];
        if (t < R) gbase[t] = atomicAdd(&gcur[t * GCS], v);
        incl = v;
        for (int o = 1; o < 64; o <<= 1) {
            unsigned up = __shfl_up(incl, o, 64);
            if ((t & 63) >= o) incl += up;
        }
        if ((t & 63) == 63) wsum[t >> 6] = incl;
    }
    __syncthreads();
    if (t < MAXR) {
        unsigned add = 0;
        int w = t >> 6;
        for (int k = 0; k < w; k++) add += wsum[k];
        if (t < R) lbase[t] = incl + add - v;
    }
    __syncthreads();
#pragma unroll
    for (int k = 0; k < RPT; k++) {
        if (brk[k] != 0xFFFFFFFFu) {
            unsigned b = brk[k] >> 12, r = brk[k] & 4095u;
            unsigned pos = lbase[b] + r;
            staged[pos] = make_uint2(key[k], __float_as_uint(val[k]));
            bof[pos] = (unsigned char)b;
        }
    }
    __syncthreads();
    for (int i = t; i < n; i += 512) {
        unsigned b = bof[i];
        unsigned slot = gbase[b] + (unsigned)i - lbase[b];
        if (slot < (unsigned)CAP) slab[(size_t)b * CAP + slot] = staged[i];
    }
    // block ea-sum -> epart8 (8 spread accumulators, native global f32 atomic)
    esum[t] = easc;
    __syncthreads();
    for (int o = 256; o > 0; o >>= 1) {
        if (t < o) esum[t] += esum[t + o];
        __syncthreads();
    }
    if (t == 0) unsafeAtomicAdd(&epart8[blockIdx.x & 7], esum[0]);
}

// ---- phase 2: per (slice s, bucket r): LDS aggregation; 3 packed-f16 atomics/record ----
// accH[dl*HSTR + c]: c0={ex*x0,ex*x1}, c1={ex*x2,ex*x3}, c2={ex*x4, ex}
// partials layout (SoA, half2): [r][s][3][NPB] u32
__global__ void k_p2(const uint2* __restrict__ slab, const unsigned* __restrict__ gcur,
                     const uint4* __restrict__ xh, const float* __restrict__ a_d,
                     unsigned* __restrict__ partials, const float* __restrict__ epart8,
                     float* __restrict__ consts_w, int S, int CAP, int N) {
    __shared__ __half2 accH[NPB * HSTR];   // 10 KB
    __shared__ float adl[NPB];             // 2 KB
    int t = threadIdx.x;  // 256
    int s = blockIdx.x, r = blockIdx.y;
    if (s == 0 && r == 0 && t == 0) {
        float se = 0.f;
        for (int i = 0; i < 8; i++) se += epart8[i];
        consts_w[0] = se;   // consumed by k_p3 (next kernel)
    }
    for (int i = t; i < NPB; i += 256) {
        int node = r * NPB + i;
        adl[i] = (node < N) ? a_d[node] : 0.f;
    }
    __half2 z2 = __floats2half2_rn(0.f, 0.f);
    for (int i = t; i < NPB * HSTR; i += 256) accH[i] = z2;
    __syncthreads();
    unsigned cnt = gcur[r * GCS]; if (cnt > (unsigned)CAP) cnt = CAP;
    unsigned L = (cnt + (unsigned)S - 1) / (unsigned)S;
    unsigned i0 = (unsigned)s * L, i1 = i0 + L; if (i1 > cnt) i1 = cnt;
    const uint2* sl = slab + (size_t)r * CAP;
    for (unsigned i = i0 + t; i < i1; i += 256) {
        uint2 rec = sl[i];
        uint4 v = xh[rec.x >> NPBL];
        unsigned dl = rec.x & (NPB - 1);
        float al = __uint_as_float(v.w) + adl[dl] + __uint_as_float(rec.y);
        float ex = __expf(lrelu(al));
        __half2 ex2 = __half2half2(__float2half(ex));
        __half2* a = accH + dl * HSTR;
        unsafeAtomicAdd(a + 0, __hmul2(ex2, *reinterpret_cast<const __half2*>(&v.x)));
        unsafeAtomicAdd(a + 1, __hmul2(ex2, *reinterpret_cast<const __half2*>(&v.y)));
        unsafeAtomicAdd(a + 2, __hmul2(ex2, *reinterpret_cast<const __half2*>(&v.z)));
    }
    __syncthreads();
    // SoA half2 writeout: out[comp*NPB + dl] = accH[dl*HSTR + comp]
    unsigned* out = partials + (size_t)(r * S + s) * (NPB * 3);
    for (int j = t; j < NPB * 3; j += 256) {
        int comp = j >> NPBL, dl = j & (NPB - 1);
        out[j] = *reinterpret_cast<unsigned*>(&accH[dl * HSTR + comp]);
    }
}

// ---- phase 3: merge S half2 partials + self-loop, normalize -> y SoA [5][N] ----
__global__ void k_p3(const unsigned* __restrict__ partials, const float* __restrict__ x,
                     const float* __restrict__ a_s, const float* __restrict__ a_d,
                     const float* __restrict__ consts, float* __restrict__ y,
                     int N, int S, float inv_E) {
    int i = blockIdx.x * blockDim.x + threadIdx.x;
    if (i >= N) return;
    int r = i >> NPBL, dl = i & (NPB - 1);
    float2 y01 = make_float2(0.f, 0.f), y23 = make_float2(0.f, 0.f), y4s = make_float2(0.f, 0.f);
    const unsigned* p = partials + (size_t)r * S * (NPB * 3) + dl;
    for (int s = 0; s < S; s++) {
        const unsigned* q = p + (size_t)s * (NPB * 3);
        float2 a = up2(q[0 * NPB]), b = up2(q[1 * NPB]), c = up2(q[2 * NPB]);
        y01.x += a.x; y01.y += a.y;
        y23.x += b.x; y23.y += b.y;
        y4s.x += c.x; y4s.y += c.y;
    }
    const float* xi = x + (size_t)i * 5;
    float x0 = xi[0], x1 = xi[1], x2 = xi[2], x3 = xi[3], x4 = xi[4];
    float mean_ea = consts[0] * inv_E;
    float aself = lrelu(a_s[i] + a_d[i] + consts[1] * mean_ea);
    float exs = __expf(aself);
    float inv = 1.f / (y4s.y + exs + 1e-16f);
    y[0 * (size_t)N + i] = (y01.x + exs * x0) * inv;
    y[1 * (size_t)N + i] = (y01.y + exs * x1) * inv;
    y[2 * (size_t)N + i] = (y23.x + exs * x2) * inv;
    y[3 * (size_t)N + i] = (y23.y + exs * x3) * inv;
    y[4 * (size_t)N + i] = (y4s.x + exs * x4) * inv;
}

// ---- fused pool + head: one block per batch row; 512 threads ----
__global__ void k_poolhead(const float* __restrict__ y, const float* __restrict__ consts,
                           const int* __restrict__ bstart, const float* __restrict__ agent_state,
                           const float* __restrict__ W_fc2, const float* __restrict__ b_fc2,
                           const float* __restrict__ W_v1, const float* __restrict__ b_v1,
                           const float* __restrict__ W_v2, const float* __restrict__ b_v2,
                           const float* __restrict__ W_a1, const float* __restrict__ b_a1,
                           const float* __restrict__ W_a2, const float* __restrict__ b_a2,
                           float* __restrict__ out, int A, int B, int N) {
    __shared__ float part[4][128];
    __shared__ float gpart[4][128];
    __shared__ float z[192];
    __shared__ float va[256];      // [0:128) v1s, [128:256) a1s
    __shared__ float red[128];
    __shared__ float advs[8];
    int b = blockIdx.x, t = threadIdx.x;  // 512 threads
    int col = t & 127, grp = t >> 7;
    int st = bstart[b], en = bstart[b + 1];
    int len = en - st;
    // phase A: pool quarter `grp` for channel `col`
    {
        int qlen = (len + 3) >> 2;
        int i0 = st + grp * qlen;
        int i1 = i0 + qlen;
        if (i0 > en) i0 = en;
        if (i1 > en) i1 = en;
        float w0 = consts[144 + col], w1 = consts[272 + col], w2 = consts[400 + col],
              w3 = consts[528 + col], w4 = consts[656 + col];
        float bc = consts[16 + col];
        const float* y0 = y;
        const float* y1p = y + (size_t)N;
        const float* y2p = y + 2 * (size_t)N;
        const float* y3p = y + 3 * (size_t)N;
        const float* y4p = y + 4 * (size_t)N;
        float a0 = 0.f, a1 = 0.f, a2 = 0.f, a3 = 0.f;
        int i = i0;
        for (; i + 3 < i1; i += 4) {
            float h0 = bc + y0[i] * w0 + y1p[i] * w1 + y2p[i] * w2 + y3p[i] * w3 + y4p[i] * w4;
            float h1 = bc + y0[i+1] * w0 + y1p[i+1] * w1 + y2p[i+1] * w2 + y3p[i+1] * w3 + y4p[i+1] * w4;
            float h2 = bc + y0[i+2] * w0 + y1p[i+2] * w1 + y2p[i+2] * w2 + y3p[i+2] * w3 + y4p[i+2] * w4;
            float h3 = bc + y0[i+3] * w0 + y1p[i+3] * w1 + y2p[i+3] * w2 + y3p[i+3] * w3 + y4p[i+3] * w4;
            a0 += fmaxf(h0, 0.f);
            a1 += fmaxf(h1, 0.f);
            a2 += fmaxf(h2, 0.f);
            a3 += fmaxf(h3, 0.f);
        }
        for (; i < i1; ++i) {
            float h = bc + y0[i] * w0 + y1p[i] * w1 + y2p[i] * w2 + y3p[i] * w3 + y4p[i] * w4;
            a0 += fmaxf(h, 0.f);
        }
        part[grp][col] = (a0 + a1) + (a2 + a3);
    }
    __syncthreads();
    // phase B: z assembly + fc2
    if (t < 128) {
        float cnt = (float)len;
        cnt = cnt < 1.f ? 1.f : cnt;
        z[t] = (part[0][t] + part[1][t] + part[2][t] + part[3][t]) / cnt;
    } else if (t < 192) {
        int c = t - 128;
        float a = b_fc2[c];
        const float* as_ = agent_state + b * 34;
        for (int k = 0; k < 34; k++) a += as_[k] * W_fc2[k * 64 + c];
        z[128 + c] = fmaxf(a, 0.f);
    }
    __syncthreads();
    // phase C: grp 0/1 value GEMV halves; grp 2/3 advantage GEMV halves
    {
        const float* W = (grp & 2) ? W_a1 : W_v1;
        int j0 = (grp & 1) * 96;
        float c0 = 0.f, c1 = 0.f, c2 = 0.f, c3 = 0.f;
        for (int j = j0; j < j0 + 96; j += 4) {
            c0 += z[j]     * W[(size_t)j * 128 + col];
            c1 += z[j + 1] * W[(size_t)(j + 1) * 128 + col];
            c2 += z[j + 2] * W[(size_t)(j + 2) * 128 + col];
            c3 += z[j + 3] * W[(size_t)(j + 3) * 128 + col];
        }
        gpart[grp][col] = (c0 + c1) + (c2 + c3);
    }
    __syncthreads();
    if (t < 128) {
        float v = fmaxf(b_v1[t] + gpart[0][t] + gpart[1][t], 0.f);
        va[t] = v;
        red[t] = v * W_v2[t];
    } else if (t < 256) {
        va[t] = fmaxf(b_a1[col] + gpart[2][col] + gpart[3][col], 0.f);
    }
    __syncthreads();
    for (int o = 64; o > 0; o >>= 1) {
        if (t < o) red[t] += red[t + o];
        __syncthreads();
    }
    // advs: one 64-lane wave per output column (A<=7 -> waves 0..6)
    if (t < A * 64) {
        int oc = t >> 6, lane = t & 63;
        float s = va[128 + lane] * W_a2[(size_t)lane * A + oc]
                + va[128 + 64 + lane] * W_a2[(size_t)(64 + lane) * A + oc];
        for (int o = 32; o > 0; o >>= 1) s += __shfl_down(s, o, 64);
        if (lane == 0) advs[oc] = s + b_a2[oc];
    }
    __syncthreads();
    if (t == 0) {
        float value = red[0] + b_v2[0];
        float m = 0.f;
        for (int j = 0; j < A; j++) m += advs[j];
        m *= (1.f / (float)A);
        for (int j = 0; j < A; j++) out[b * A + j] = value + advs[j] - m;
    }
}

extern "C" void kernel_launch(void* const* d_in, const int* in_sizes, int n_in,
                              void* d_out, int out_size, void* d_ws, size_t ws_size,
                              hipStream_t stream) {
    const float* x        = (const float*)d_in[0];
    const int* edge_index = (const int*)d_in[1];
    const float* ea       = (const float*)d_in[2];
    const float* agent    = (const float*)d_in[3];
    const int* pool_batch = (const int*)d_in[4];
    const float* W_gat    = (const float*)d_in[5];
    const float* att_src  = (const float*)d_in[6];
    const float* att_dst  = (const float*)d_in[7];
    const float* W_edge   = (const float*)d_in[8];
    const float* att_edge = (const float*)d_in[9];
    const float* b_gat    = (const float*)d_in[10];
    const float* W_fc1    = (const float*)d_in[11];
    const float* b_fc1    = (const float*)d_in[12];
    const float* W_fc2    = (const float*)d_in[13];
    const float* b_fc2    = (const float*)d_in[14];
    const float* W_v1     = (const float*)d_in[15];
    const float* b_v1     = (const float*)d_in[16];
    const float* W_v2     = (const float*)d_in[17];
    const float* b_v2     = (const float*)d_in[18];
    const float* W_a1     = (const float*)d_in[19];
    const float* b_a1     = (const float*)d_in[20];
    const float* W_a2     = (const float*)d_in[21];
    const float* b_a2     = (const float*)d_in[22];

    const int N = in_sizes[0] / 5;
    const int E = in_sizes[2];
    const int B = in_sizes[3] / 34;
    const int A = out_size / B;
    const float inv_E = 1.0f / (float)E;

    const int* src = edge_index;
    const int* dst = edge_index + E;

    const int R = (N + NPB - 1) / NPB;            // 200 buckets
    int capBase = (E + R - 1) / R;                // ~8192
    const int CAP = capBase + capBase / 16 + 256;

    // ---- ws layout (no host-side zeroing; k_setup zeroes gcur/epart8) ----
    char* ws = (char*)d_ws;
    size_t off = 0;
    auto take = [&](size_t bytes) {
        size_t o = off;
        off = (off + bytes + 255) & ~(size_t)255;
        return o;
    };
    size_t o_consts = take(4096);
    size_t o_gcur   = take((size_t)MAXR * GCS * 4);
    size_t o_epart8 = take(8 * 4);
    size_t o_xh     = take((size_t)N * 16);
    size_t o_as     = take((size_t)N * 4);
    size_t o_ad     = take((size_t)N * 4);
    size_t o_y      = take((size_t)N * 5 * 4);
    size_t o_bstart = take((size_t)(B + 1) * 4);
    size_t o_slab   = take((size_t)R * CAP * 8);
    size_t o_part   = off;
    size_t perS = (size_t)R * NPB * 3 * 4;   // half2 partials
    int S = SLICES;
    while (S > 1 && o_part + (size_t)S * perS > ws_size) S--;

    float* consts   = (float*)(ws + o_consts);
    unsigned* gcur  = (unsigned*)(ws + o_gcur);
    float* epart8   = (float*)(ws + o_epart8);
    uint4* xh       = (uint4*)(ws + o_xh);
    float* a_s      = (float*)(ws + o_as);
    float* a_d      = (float*)(ws + o_ad);
    float* y        = (float*)(ws + o_y);
    int* bstart     = (int*)(ws + o_bstart);
    uint2* slab     = (uint2*)(ws + o_slab);
    unsigned* partials = (unsigned*)(ws + o_part);

    k_setup<<<1, 128, 0, stream>>>(W_gat, att_src, att_dst, W_edge, att_edge, b_gat,
                                   W_fc1, b_fc1, consts, gcur, epart8);

    int nbl = (N + 511) / 512;
    int ebl = (E + TILE - 1) / TILE;
    k_np1<<<nbl + ebl, 512, 0, stream>>>(x, consts, xh, a_s, a_d, pool_batch, bstart,
                                         src, dst, ea, slab, gcur, epart8,
                                         N, B, E, R, CAP, nbl);
    dim3 g2grid(S, R);
    k_p2<<<g2grid, 256, 0, stream>>>(slab, gcur, xh, a_d, partials, epart8, consts, S, CAP, N);
    k_p3<<<(N + 255) / 256, 256, 0, stream>>>(partials, x, a_s, a_d, consts, y, N, S, inv_E);
    k_poolhead<<<B, 512, 0, stream>>>(y, consts, bstart, agent, W_fc2, b_fc2,
                                      W_v1, b_v1, W_v2, b_v2, W_a1, b_a1, W_a2, b_a2,
                                      (float*)d_out, A, B, N);
}